// Round 8
// baseline (255.202 us; speedup 1.0000x reference)
//
#include <hip/hip_runtime.h>

// MultiHeadedAttention: B=1, S=4096, E=1024, H=16, D=64, fp32 in/out.
// f16 MFMA (fp32 accum); flash attention with no-max softmax (scale folded
// into Q, exp2 domain). S^T = mfma(Kfrag,Qfrag); P^T exits in C-layout and,
// via the key permutation baked into V^T storage, feeds directly as the
// B-operand of 16x16x32 MFMAs for PV and the row-sum (ones) MFMA. P never
// touches LDS. Key-parity wave specialization (8 waves, 16 waves/CU).
// Body is software-pipelined: exp/pack of key-half 0 overlaps S^T MFMAs of
// key-half 1; PV MFMAs of half 0 overlap exp of half 1; V-frag ds_reads
// hoisted under the exp VALU phase.

constexpr int Sq = 4096;
constexpr int Ee = 1024;
constexpr int Hh = 16;
constexpr int Dh = 64;

typedef _Float16 half8 __attribute__((ext_vector_type(8)));
typedef _Float16 half4 __attribute__((ext_vector_type(4)));
typedef _Float16 half2t __attribute__((ext_vector_type(2)));
typedef float f32x4 __attribute__((ext_vector_type(4)));

union U8 { half8 v8; half2t h2[4]; };

__device__ __forceinline__ unsigned short f2h(float f) {
  _Float16 h = (_Float16)f;
  return *reinterpret_cast<unsigned short*>(&h);
}

__device__ __forceinline__ half2t pk(float a, float b) {
  return __builtin_bit_cast(half2t, __builtin_amdgcn_cvt_pkrtz(a, b));
}

__device__ __forceinline__ void gload16(const void* g, void* l) {
  __builtin_amdgcn_global_load_lds(
      (const __attribute__((address_space(1))) void*)g,
      (__attribute__((address_space(3))) void*)l, 16, 0, 0);
}

// ---- fused prep: x fp32->f16 (blocks 0..4095) + 4 weight transposes ----
__global__ void k_prep(const float* __restrict__ x,
                       const float* __restrict__ Wq, const float* __restrict__ Wk,
                       const float* __restrict__ Wv, const float* __restrict__ Wo,
                       unsigned short* __restrict__ xb,
                       unsigned short* __restrict__ Wqt, unsigned short* __restrict__ Wkt,
                       unsigned short* __restrict__ Wvt, unsigned short* __restrict__ Wot) {
  int b = blockIdx.x, t = threadIdx.x;
  if (b < 4096) {
    int i = b * 256 + t;
    float4 v = reinterpret_cast<const float4*>(x)[i];
    ushort4 o;
    o.x = f2h(v.x); o.y = f2h(v.y); o.z = f2h(v.z); o.w = f2h(v.w);
    reinterpret_cast<ushort4*>(xb)[i] = o;
    return;
  }
  __shared__ unsigned short tile[64][65];
  int r = b - 4096;
  int wi = r >> 8, ti = r & 255;
  const float* W = (wi == 0) ? Wq : (wi == 1) ? Wk : (wi == 2) ? Wv : Wo;
  unsigned short* Wt = (wi == 0) ? Wqt : (wi == 1) ? Wkt : (wi == 2) ? Wvt : Wot;
  int kb = (ti & 15) * 64, nb = (ti >> 4) * 64;
  int r0 = t >> 4, c4 = (t & 15) * 4;
  for (int i = 0; i < 4; i++) {
    int row = r0 + i * 16;
    float4 v = *reinterpret_cast<const float4*>(W + (size_t)(kb + row) * Ee + nb + c4);
    tile[row][c4 + 0] = f2h(v.x); tile[row][c4 + 1] = f2h(v.y);
    tile[row][c4 + 2] = f2h(v.z); tile[row][c4 + 3] = f2h(v.w);
  }
  __syncthreads();
  for (int i = 0; i < 4; i++) {
    int nrow = r0 + i * 16;
    ushort4 o;
    o.x = tile[c4 + 0][nrow]; o.y = tile[c4 + 1][nrow];
    o.z = tile[c4 + 2][nrow]; o.w = tile[c4 + 3][nrow];
    *reinterpret_cast<ushort4*>(Wt + (size_t)(nb + nrow) * Ee + kb + c4) = o;
  }
}

// ---- GEMM K-loop (shared); TR=1 computes C^T (W-frag as A-operand) ----
template <bool TR>
__device__ __forceinline__ void gemm_kloop(
    const unsigned short* __restrict__ A, const unsigned short* __restrict__ Wt,
    unsigned short* Al, unsigned short* Bl,
    int m0, int n0, int t, int wm, int wn, int quad, int c, f32x4 (&acc)[4][4]) {
  for (int k0 = 0; k0 < 1024; k0 += 64) {
    __syncthreads();
#pragma unroll
    for (int i = 0; i < 4; i++) {
      int ch = i * 256 + t;
      int row = ch >> 3, kg = (ch & 7) ^ (row & 7);
      gload16(A + (size_t)(m0 + row) * 1024 + k0 + kg * 8, &Al[ch * 8]);
    }
#pragma unroll
    for (int i = 0; i < 4; i++) {
      int ch = i * 256 + t;
      int row = ch >> 3, kg = (ch & 7) ^ (row & 7);
      gload16(Wt + (size_t)(n0 + row) * 1024 + k0 + kg * 8, &Bl[ch * 8]);
    }
    __syncthreads();
#pragma unroll
    for (int ks = 0; ks < 2; ks++) {
      half8 af[4], bfr[4];
#pragma unroll
      for (int i = 0; i < 4; i++) {
        int row = wm * 64 + i * 16 + c;
        int kg = (quad + 4 * ks) ^ (row & 7);
        af[i] = *reinterpret_cast<const half8*>(&Al[row * 64 + kg * 8]);
      }
#pragma unroll
      for (int j = 0; j < 4; j++) {
        int row = wn * 64 + j * 16 + c;
        int kg = (quad + 4 * ks) ^ (row & 7);
        bfr[j] = *reinterpret_cast<const half8*>(&Bl[row * 64 + kg * 8]);
      }
#pragma unroll
      for (int i = 0; i < 4; i++)
#pragma unroll
        for (int j = 0; j < 4; j++) {
          if (TR)
            acc[j][i] = __builtin_amdgcn_mfma_f32_16x16x32_f16(bfr[j], af[i], acc[j][i], 0, 0, 0);
          else
            acc[i][j] = __builtin_amdgcn_mfma_f32_16x16x32_f16(af[i], bfr[j], acc[i][j], 0, 0, 0);
        }
    }
  }
}

// ---- GEMM: A[M][1024] f16 row-major  @  Wt[n][k] f16  (+bias)
// mode 0, z 0/1 (Q/K): C^T, half4 stores to [h][s][d]; Q pre-scaled by
//   0.125*log2e.  mode 0, z 2 (V): C, writes V^T [h][d][perm(s)] half4.
// mode 1: C^T, float4 stores to fp32 [s][1024].
__global__ __launch_bounds__(256) void k_gemm(
    const unsigned short* __restrict__ A,
    const unsigned short* __restrict__ W0, const unsigned short* __restrict__ W1,
    const unsigned short* __restrict__ W2,
    const float* __restrict__ b0, const float* __restrict__ b1, const float* __restrict__ b2,
    void* d0, void* d1, void* d2, int mode) {
  __shared__ __align__(16) unsigned short Al[128 * 64];
  __shared__ __align__(16) unsigned short Bl[128 * 64];
  const unsigned short* Wt; const float* bias; void* dst;
  if (blockIdx.z == 0)      { Wt = W0; bias = b0; dst = d0; }
  else if (blockIdx.z == 1) { Wt = W1; bias = b1; dst = d1; }
  else                      { Wt = W2; bias = b2; dst = d2; }

  int t = threadIdx.x;
  int w = t >> 6, L = t & 63, quad = L >> 4, c = L & 15;
  int m0 = blockIdx.x * 128, n0 = blockIdx.y * 128;
  int wm = w >> 1, wn = w & 1;

  f32x4 zero = {0.f, 0.f, 0.f, 0.f};
  f32x4 acc[4][4];
#pragma unroll
  for (int i = 0; i < 4; i++)
#pragma unroll
    for (int j = 0; j < 4; j++) acc[i][j] = zero;

  bool tr = (mode == 1) || (blockIdx.z < 2);
  if (tr) gemm_kloop<true>(A, Wt, Al, Bl, m0, n0, t, wm, wn, quad, c, acc);
  else    gemm_kloop<false>(A, Wt, Al, Bl, m0, n0, t, wm, wn, quad, c, acc);

  if (mode == 1) {  // fp32 [s][1024], C^T: regs hold 4 consecutive n
    float* out = (float*)dst;
#pragma unroll
    for (int j = 0; j < 4; j++) {
      int nb4 = n0 + wn * 64 + j * 16 + quad * 4;
      f32x4 b4 = *reinterpret_cast<const f32x4*>(bias + nb4);
#pragma unroll
      for (int i = 0; i < 4; i++) {
        int s = m0 + wm * 64 + i * 16 + c;
        f32x4 v = acc[j][i] + b4;
        *reinterpret_cast<f32x4*>(out + (size_t)s * 1024 + nb4) = v;
      }
    }
    return;
  }
  if (blockIdx.z < 2) {  // Q/K f16 [h][s][d], C^T: regs hold 4 consecutive d
    float sc = (blockIdx.z == 0) ? 0.18033688011112042f : 1.0f;
    unsigned short* qk = (unsigned short*)dst;
#pragma unroll
    for (int j = 0; j < 4; j++) {
      int nb4 = n0 + wn * 64 + j * 16 + quad * 4;
      int hh = nb4 >> 6, d = nb4 & 63;
      f32x4 b4 = *reinterpret_cast<const f32x4*>(bias + nb4);
#pragma unroll
      for (int i = 0; i < 4; i++) {
        int s = m0 + wm * 64 + i * 16 + c;
        half4 hv;
#pragma unroll
        for (int r = 0; r < 4; r++) hv[r] = (_Float16)((acc[j][i][r] + b4[r]) * sc);
        *reinterpret_cast<half4*>(&qk[(size_t)hh * Sq * Dh + (size_t)s * Dh + d]) = hv;
      }
    }
    return;
  }
  // V: write transposed+permuted [h][d][perm(s)], half4 per (i,j) (C layout)
  unsigned short* Vt = (unsigned short*)dst;
#pragma unroll
  for (int j = 0; j < 4; j++) {
    int n = n0 + wn * 64 + j * 16 + c;
    int hh = n >> 6, d = n & 63;
    float bv = bias[n];
#pragma unroll
    for (int i = 0; i < 4; i++) {
      int pos = m0 + wm * 64 + (i >> 1) * 32 + quad * 8 + (i & 1) * 4;
      half4 hv;
#pragma unroll
      for (int r = 0; r < 4; r++) hv[r] = (_Float16)(acc[i][j][r] + bv);
      *reinterpret_cast<half4*>(&Vt[(size_t)hh * Dh * Sq + (size_t)d * Sq + pos]) = hv;
    }
  }
}

// ---- flash attention, S^T/O^T form, all-K=32 MFMA, key-parity waves ----
// Q,K [h][s][64] f16 (Q pre-scaled), Vt [h][64][perm(s)] f16 -> O [s][1024] f16
// 512 threads = 8 waves; wave w: parity par=w>>2 (even/odd key tiles),
// wl=w&3 owns 32 q-rows. LDS: [buf][Kev,Kod,Vev,Vod][8KB] = 64KB.
__global__ __launch_bounds__(512, 4) void k_attn(
    const unsigned short* __restrict__ Q, const unsigned short* __restrict__ K,
    const unsigned short* __restrict__ Vt, unsigned short* __restrict__ O) {
  __shared__ __align__(16) unsigned short SM[32768];  // 64 KB
  int t = threadIdx.x;
  int w = t >> 6, L = t & 63, quad = L >> 4, c = L & 15;
  int wl = w & 3, par = w >> 2;
  int h = blockIdx.y, qb = blockIdx.x;
  const unsigned short* Qh = Q + (size_t)h * Sq * Dh;
  const unsigned short* Kh = K + (size_t)h * Sq * Dh;
  const unsigned short* Vth = Vt + (size_t)h * Dh * Sq;

  // Q fragments (B-operand of S^T): lane n=c holds Q[q][d=ks*32+quad*8+j]
  half8 qf[2][2];
#pragma unroll
  for (int qg = 0; qg < 2; qg++) {
    int qrow = qb * 128 + wl * 32 + qg * 16 + c;
#pragma unroll
    for (int ks = 0; ks < 2; ks++)
      qf[qg][ks] = *reinterpret_cast<const half8*>(Qh + (size_t)qrow * Dh + ks * 32 + quad * 8);
  }

  f32x4 zero = {0.f, 0.f, 0.f, 0.f};
  f32x4 o0[4], o1[4];
#pragma unroll
  for (int i = 0; i < 4; i++) { o0[i] = zero; o1[i] = zero; }
  f32x4 l0 = zero, l1 = zero;
  half8 ones8;
#pragma unroll
  for (int j = 0; j < 8; j++) ones8[j] = (_Float16)1.0f;

  // hoisted LDS read offsets (elements; include parity tile base)
  int koff[2][4], voff[4][2];
#pragma unroll
  for (int ks = 0; ks < 2; ks++)
#pragma unroll
    for (int nt = 0; nt < 4; nt++) {
      int row = nt * 16 + c;
      koff[ks][nt] = par * 4096 + row * 64 + (((ks * 4 + quad) ^ (row & 7)) * 8);
    }
#pragma unroll
  for (int dt = 0; dt < 4; dt++)
#pragma unroll
    for (int n2 = 0; n2 < 2; n2++) {
      int row = dt * 16 + c;
      voff[dt][n2] = (2 + par) * 4096 + row * 64 + (((n2 * 4 + quad) ^ (row & 7)) * 8);
    }

  // staging base pointers (lane-dependent part hoisted)
  int srow = t >> 3, skg = (t & 7) ^ (srow & 7);
  const unsigned short* Kg = Kh + srow * Dh + skg * 8;          // + tb*4096
  const unsigned short* Vg = Vth + (size_t)srow * Sq + skg * 8; // + tb*64

  // stage key tiles 0,1 into buf0
#pragma unroll
  for (int p2 = 0; p2 < 2; p2++) {
    gload16(Kg + p2 * 4096, &SM[p2 * 4096 + t * 8]);
    gload16(Vg + p2 * 64, &SM[(2 + p2) * 4096 + t * 8]);
  }

  // software-pipelined body: exp(half0) overlaps S^T(half1) MFMAs;
  // PV(half0) MFMAs overlap exp(half1); vv ds_reads hide under exp.
  auto body = [&](int BUFOFF) {
    f32x4 st0[4], st1[4];
#pragma unroll
    for (int nt = 0; nt < 4; nt++) { st0[nt] = zero; st1[nt] = zero; }
    // (a)+(b): S^T MFMAs, halves in order nt={0,1} then {2,3}
#pragma unroll
    for (int nt = 0; nt < 4; nt++)
#pragma unroll
      for (int ks = 0; ks < 2; ks++) {
        half8 kfv = *reinterpret_cast<const half8*>(&SM[koff[ks][nt] + BUFOFF]);
        st0[nt] = __builtin_amdgcn_mfma_f32_16x16x32_f16(kfv, qf[0][ks], st0[nt], 0, 0, 0);
        st1[nt] = __builtin_amdgcn_mfma_f32_16x16x32_f16(kfv, qf[1][ks], st1[nt], 0, 0, 0);
      }
#pragma unroll
    for (int n2 = 0; n2 < 2; n2++) {
      // (v): hoist V-frag reads for this half — latency hides under exp
      half8 vv[4];
#pragma unroll
      for (int dt = 0; dt < 4; dt++)
        vv[dt] = *reinterpret_cast<const half8*>(&SM[voff[dt][n2] + BUFOFF]);
      // (c)/(e): exp + pack this half (VALU) — overlaps in-flight MFMAs
      U8 u;
      u.h2[0] = pk(__builtin_amdgcn_exp2f(st0[2 * n2][0]), __builtin_amdgcn_exp2f(st0[2 * n2][1]));
      u.h2[1] = pk(__builtin_amdgcn_exp2f(st0[2 * n2][2]), __builtin_amdgcn_exp2f(st0[2 * n2][3]));
      u.h2[2] = pk(__builtin_amdgcn_exp2f(st0[2 * n2 + 1][0]), __builtin_amdgcn_exp2f(st0[2 * n2 + 1][1]));
      u.h2[3] = pk(__builtin_amdgcn_exp2f(st0[2 * n2 + 1][2]), __builtin_amdgcn_exp2f(st0[2 * n2 + 1][3]));
      half8 pB0 = u.v8;
      U8 v;
      v.h2[0] = pk(__builtin_amdgcn_exp2f(st1[2 * n2][0]), __builtin_amdgcn_exp2f(st1[2 * n2][1]));
      v.h2[1] = pk(__builtin_amdgcn_exp2f(st1[2 * n2][2]), __builtin_amdgcn_exp2f(st1[2 * n2][3]));
      v.h2[2] = pk(__builtin_amdgcn_exp2f(st1[2 * n2 + 1][0]), __builtin_amdgcn_exp2f(st1[2 * n2 + 1][1]));
      v.h2[3] = pk(__builtin_amdgcn_exp2f(st1[2 * n2 + 1][2]), __builtin_amdgcn_exp2f(st1[2 * n2 + 1][3]));
      half8 pB1 = v.v8;
      // (d)/(f): row-sum + PV MFMAs for this half
      l0 = __builtin_amdgcn_mfma_f32_16x16x32_f16(ones8, pB0, l0, 0, 0, 0);
      l1 = __builtin_amdgcn_mfma_f32_16x16x32_f16(ones8, pB1, l1, 0, 0, 0);
#pragma unroll
      for (int dt = 0; dt < 4; dt++) {
        o0[dt] = __builtin_amdgcn_mfma_f32_16x16x32_f16(vv[dt], pB0, o0[dt], 0, 0, 0);
        o1[dt] = __builtin_amdgcn_mfma_f32_16x16x32_f16(vv[dt], pB1, o1[dt], 0, 0, 0);
      }
    }
  };

  for (int ob2 = 0; ob2 < 16; ob2++) {
    // sub-iter A: compute buf0 (key tiles 4*ob2+{0,1}); stage 4*ob2+{2,3} -> buf1
    __syncthreads();
    {
      int tb = 4 * ob2 + 2;
#pragma unroll
      for (int p2 = 0; p2 < 2; p2++) {
        gload16(Kg + (size_t)(tb + p2) * 4096, &SM[16384 + p2 * 4096 + t * 8]);
        gload16(Vg + (tb + p2) * 64, &SM[16384 + (2 + p2) * 4096 + t * 8]);
      }
    }
    body(0);
    // sub-iter B: compute buf1 (key tiles 4*ob2+{2,3}); stage 4*ob2+{4,5} -> buf0
    __syncthreads();
    if (ob2 < 15) {
      int tb = 4 * ob2 + 4;
#pragma unroll
      for (int p2 = 0; p2 < 2; p2++) {
        gload16(Kg + (size_t)(tb + p2) * 4096, &SM[p2 * 4096 + t * 8]);
        gload16(Vg + (tb + p2) * 64, &SM[(2 + p2) * 4096 + t * 8]);
      }
    }
    body(16384);
  }

  // combine even/odd partials: plain sums -> exact addition.
  __syncthreads();  // all LDS tile reads done
  float* cb = (float*)SM;  // [wl][vec 0..8][lane] of f32x4 = 36 KB
  if (par == 1) {
#pragma unroll
    for (int v = 0; v < 4; v++) {
      *reinterpret_cast<f32x4*>(cb + ((wl * 9 + v) * 64 + L) * 4) = o0[v];
      *reinterpret_cast<f32x4*>(cb + ((wl * 9 + 4 + v) * 64 + L) * 4) = o1[v];
    }
    f32x4 lv = {l0[0], l1[0], 0.f, 0.f};
    *reinterpret_cast<f32x4*>(cb + ((wl * 9 + 8) * 64 + L) * 4) = lv;
  }
  __syncthreads();
  if (par == 0) {
#pragma unroll
    for (int v = 0; v < 4; v++) {
      o0[v] += *reinterpret_cast<const f32x4*>(cb + ((wl * 9 + v) * 64 + L) * 4);
      o1[v] += *reinterpret_cast<const f32x4*>(cb + ((wl * 9 + 4 + v) * 64 + L) * 4);
    }
    f32x4 lv = *reinterpret_cast<const f32x4*>(cb + ((wl * 9 + 8) * 64 + L) * 4);
    float lt0 = l0[0] + lv[0], lt1 = l1[0] + lv[1];

    // epilogue: O^T lane holds q=c, d = dt*16+quad*4+r
#pragma unroll
    for (int qg = 0; qg < 2; qg++) {
      float inv = 1.f / (qg ? lt1 : lt0);
      f32x4* oo = qg ? o1 : o0;
      int q = qb * 128 + wl * 32 + qg * 16 + c;
#pragma unroll
      for (int dt = 0; dt < 4; dt++) {
        half4 hv;
#pragma unroll
        for (int r = 0; r < 4; r++) hv[r] = (_Float16)(oo[dt][r] * inv);
        *reinterpret_cast<half4*>(&O[(size_t)q * 1024 + h * 64 + dt * 16 + quad * 4]) = hv;
      }
    }
  }
}

extern "C" void kernel_launch(void* const* d_in, const int* in_sizes, int n_in,
                              void* d_out, int out_size, void* d_ws, size_t ws_size,
                              hipStream_t stream) {
  const float* x  = (const float*)d_in[0];
  const float* Wq = (const float*)d_in[1];
  const float* bq = (const float*)d_in[2];
  const float* Wk = (const float*)d_in[3];
  const float* bk = (const float*)d_in[4];
  const float* Wv = (const float*)d_in[5];
  const float* bv = (const float*)d_in[6];
  const float* Wo = (const float*)d_in[7];
  const float* bo = (const float*)d_in[8];

  char* ws = (char*)d_ws;
  const size_t MB = 1u << 20;
  unsigned short* xb  = (unsigned short*)(ws);            // 8 MB  x as f16
  unsigned short* Wqt = (unsigned short*)(ws + 8 * MB);   // 2 MB each, transposed f16
  unsigned short* Wkt = (unsigned short*)(ws + 10 * MB);
  unsigned short* Wvt = (unsigned short*)(ws + 12 * MB);
  unsigned short* Wot = (unsigned short*)(ws + 14 * MB);
  unsigned short* Qb  = (unsigned short*)(ws + 16 * MB);  // 8 MB [h][s][d]
  unsigned short* Kb  = (unsigned short*)(ws + 24 * MB);  // 8 MB [h][s][d]
  unsigned short* Vtg = (unsigned short*)(ws + 32 * MB);  // 8 MB [h][d][perm(s)]
  unsigned short* Ob  = (unsigned short*)(ws + 40 * MB);  // 8 MB [s][e]  (total 48 MB)

  k_prep<<<5120, 256, 0, stream>>>(x, Wq, Wk, Wv, Wo, xb, Wqt, Wkt, Wvt, Wot);
  k_gemm<<<dim3(32, 8, 3), 256, 0, stream>>>(xb, Wqt, Wkt, Wvt, bq, bk, bv,
                                             (void*)Qb, (void*)Kb, (void*)Vtg, 0);
  k_attn<<<dim3(32, 16), 512, 0, stream>>>(Qb, Kb, Vtg, Ob);
  k_gemm<<<dim3(32, 8, 1), 256, 0, stream>>>(Ob, Wot, Wot, Wot, bo, bo, bo,
                                             d_out, d_out, d_out, 1);
}

// Round 9
// 229.443 us; speedup vs baseline: 1.1123x; 1.1123x over previous
//
#include <hip/hip_runtime.h>

// MultiHeadedAttention: B=1, S=4096, E=1024, H=16, D=64, fp32 in/out.
// f16 MFMA (fp32 accum); flash attention with no-max softmax (scale folded
// into Q, exp2 domain). S^T = mfma(Kfrag,Qfrag); P^T exits in C-layout and,
// via the key permutation baked into V^T storage, feeds directly as the
// B-operand of 16x16x32 MFMAs for PV and the row-sum (ones) MFMA. P never
// touches LDS. Key-parity wave specialization (8 waves, 16 waves/CU).
// NOTE (R8 post-mortem): in-wave software pipelining of the attn body
// spills to scratch (WRITE_SIZE 8->73MB) — body must stay in R7 form.

constexpr int Sq = 4096;
constexpr int Ee = 1024;
constexpr int Hh = 16;
constexpr int Dh = 64;

typedef _Float16 half8 __attribute__((ext_vector_type(8)));
typedef _Float16 half4 __attribute__((ext_vector_type(4)));
typedef _Float16 half2t __attribute__((ext_vector_type(2)));
typedef float f32x4 __attribute__((ext_vector_type(4)));

union U8 { half8 v8; half2t h2[4]; };

__device__ __forceinline__ unsigned short f2h(float f) {
  _Float16 h = (_Float16)f;
  return *reinterpret_cast<unsigned short*>(&h);
}

__device__ __forceinline__ half2t pk(float a, float b) {
  return __builtin_bit_cast(half2t, __builtin_amdgcn_cvt_pkrtz(a, b));
}

__device__ __forceinline__ void gload16(const void* g, void* l) {
  __builtin_amdgcn_global_load_lds(
      (const __attribute__((address_space(1))) void*)g,
      (__attribute__((address_space(3))) void*)l, 16, 0, 0);
}

// ---- fused prep: x fp32->f16 (blocks 0..4095) + 4 weight transposes ----
__global__ void k_prep(const float* __restrict__ x,
                       const float* __restrict__ Wq, const float* __restrict__ Wk,
                       const float* __restrict__ Wv, const float* __restrict__ Wo,
                       unsigned short* __restrict__ xb,
                       unsigned short* __restrict__ Wqt, unsigned short* __restrict__ Wkt,
                       unsigned short* __restrict__ Wvt, unsigned short* __restrict__ Wot) {
  int b = blockIdx.x, t = threadIdx.x;
  if (b < 4096) {
    int i = b * 256 + t;
    float4 v = reinterpret_cast<const float4*>(x)[i];
    ushort4 o;
    o.x = f2h(v.x); o.y = f2h(v.y); o.z = f2h(v.z); o.w = f2h(v.w);
    reinterpret_cast<ushort4*>(xb)[i] = o;
    return;
  }
  __shared__ unsigned short tile[64][65];
  int r = b - 4096;
  int wi = r >> 8, ti = r & 255;
  const float* W = (wi == 0) ? Wq : (wi == 1) ? Wk : (wi == 2) ? Wv : Wo;
  unsigned short* Wt = (wi == 0) ? Wqt : (wi == 1) ? Wkt : (wi == 2) ? Wvt : Wot;
  int kb = (ti & 15) * 64, nb = (ti >> 4) * 64;
  int r0 = t >> 4, c4 = (t & 15) * 4;
  for (int i = 0; i < 4; i++) {
    int row = r0 + i * 16;
    float4 v = *reinterpret_cast<const float4*>(W + (size_t)(kb + row) * Ee + nb + c4);
    tile[row][c4 + 0] = f2h(v.x); tile[row][c4 + 1] = f2h(v.y);
    tile[row][c4 + 2] = f2h(v.z); tile[row][c4 + 3] = f2h(v.w);
  }
  __syncthreads();
  for (int i = 0; i < 4; i++) {
    int nrow = r0 + i * 16;
    ushort4 o;
    o.x = tile[c4 + 0][nrow]; o.y = tile[c4 + 1][nrow];
    o.z = tile[c4 + 2][nrow]; o.w = tile[c4 + 3][nrow];
    *reinterpret_cast<ushort4*>(Wt + (size_t)(nb + nrow) * Ee + kb + c4) = o;
  }
}

// ---- GEMM K-loop (shared); TR=1 computes C^T (W-frag as A-operand) ----
template <bool TR>
__device__ __forceinline__ void gemm_kloop(
    const unsigned short* __restrict__ A, const unsigned short* __restrict__ Wt,
    unsigned short* Al, unsigned short* Bl,
    int m0, int n0, int t, int wm, int wn, int quad, int c, f32x4 (&acc)[4][4]) {
  for (int k0 = 0; k0 < 1024; k0 += 64) {
    __syncthreads();
#pragma unroll
    for (int i = 0; i < 4; i++) {
      int ch = i * 256 + t;
      int row = ch >> 3, kg = (ch & 7) ^ (row & 7);
      gload16(A + (size_t)(m0 + row) * 1024 + k0 + kg * 8, &Al[ch * 8]);
    }
#pragma unroll
    for (int i = 0; i < 4; i++) {
      int ch = i * 256 + t;
      int row = ch >> 3, kg = (ch & 7) ^ (row & 7);
      gload16(Wt + (size_t)(n0 + row) * 1024 + k0 + kg * 8, &Bl[ch * 8]);
    }
    __syncthreads();
#pragma unroll
    for (int ks = 0; ks < 2; ks++) {
      half8 af[4], bfr[4];
#pragma unroll
      for (int i = 0; i < 4; i++) {
        int row = wm * 64 + i * 16 + c;
        int kg = (quad + 4 * ks) ^ (row & 7);
        af[i] = *reinterpret_cast<const half8*>(&Al[row * 64 + kg * 8]);
      }
#pragma unroll
      for (int j = 0; j < 4; j++) {
        int row = wn * 64 + j * 16 + c;
        int kg = (quad + 4 * ks) ^ (row & 7);
        bfr[j] = *reinterpret_cast<const half8*>(&Bl[row * 64 + kg * 8]);
      }
#pragma unroll
      for (int i = 0; i < 4; i++)
#pragma unroll
        for (int j = 0; j < 4; j++) {
          if (TR)
            acc[j][i] = __builtin_amdgcn_mfma_f32_16x16x32_f16(bfr[j], af[i], acc[j][i], 0, 0, 0);
          else
            acc[i][j] = __builtin_amdgcn_mfma_f32_16x16x32_f16(af[i], bfr[j], acc[i][j], 0, 0, 0);
        }
    }
  }
}

// ---- QKV GEMM: A[4096][1024] f16  @  Wt[n][k] f16  (+bias) ----
// z 0/1 (Q/K): C^T, half4 stores to [h][s][d]; Q pre-scaled by 0.125*log2e.
// z 2 (V): C, writes V^T [h][d][perm(s)] half4.
__global__ __launch_bounds__(256) void k_gemm(
    const unsigned short* __restrict__ A,
    const unsigned short* __restrict__ W0, const unsigned short* __restrict__ W1,
    const unsigned short* __restrict__ W2,
    const float* __restrict__ b0, const float* __restrict__ b1, const float* __restrict__ b2,
    void* d0, void* d1, void* d2) {
  __shared__ __align__(16) unsigned short Al[128 * 64];
  __shared__ __align__(16) unsigned short Bl[128 * 64];
  const unsigned short* Wt; const float* bias; void* dst;
  if (blockIdx.z == 0)      { Wt = W0; bias = b0; dst = d0; }
  else if (blockIdx.z == 1) { Wt = W1; bias = b1; dst = d1; }
  else                      { Wt = W2; bias = b2; dst = d2; }

  int t = threadIdx.x;
  int w = t >> 6, L = t & 63, quad = L >> 4, c = L & 15;
  int m0 = blockIdx.x * 128, n0 = blockIdx.y * 128;
  int wm = w >> 1, wn = w & 1;

  f32x4 zero = {0.f, 0.f, 0.f, 0.f};
  f32x4 acc[4][4];
#pragma unroll
  for (int i = 0; i < 4; i++)
#pragma unroll
    for (int j = 0; j < 4; j++) acc[i][j] = zero;

  if (blockIdx.z < 2) gemm_kloop<true>(A, Wt, Al, Bl, m0, n0, t, wm, wn, quad, c, acc);
  else                gemm_kloop<false>(A, Wt, Al, Bl, m0, n0, t, wm, wn, quad, c, acc);

  if (blockIdx.z < 2) {  // Q/K f16 [h][s][d], C^T: regs hold 4 consecutive d
    float sc = (blockIdx.z == 0) ? 0.18033688011112042f : 1.0f;
    unsigned short* qk = (unsigned short*)dst;
#pragma unroll
    for (int j = 0; j < 4; j++) {
      int nb4 = n0 + wn * 64 + j * 16 + quad * 4;
      int hh = nb4 >> 6, d = nb4 & 63;
      f32x4 b4 = *reinterpret_cast<const f32x4*>(bias + nb4);
#pragma unroll
      for (int i = 0; i < 4; i++) {
        int s = m0 + wm * 64 + i * 16 + c;
        half4 hv;
#pragma unroll
        for (int r = 0; r < 4; r++) hv[r] = (_Float16)((acc[j][i][r] + b4[r]) * sc);
        *reinterpret_cast<half4*>(&qk[(size_t)hh * Sq * Dh + (size_t)s * Dh + d]) = hv;
      }
    }
    return;
  }
  // V: write transposed+permuted [h][d][perm(s)], half4 per (i,j) (C layout)
  unsigned short* Vt = (unsigned short*)dst;
#pragma unroll
  for (int j = 0; j < 4; j++) {
    int n = n0 + wn * 64 + j * 16 + c;
    int hh = n >> 6, d = n & 63;
    float bv = bias[n];
#pragma unroll
    for (int i = 0; i < 4; i++) {
      int pos = m0 + wm * 64 + (i >> 1) * 32 + quad * 8 + (i & 1) * 4;
      half4 hv;
#pragma unroll
      for (int r = 0; r < 4; r++) hv[r] = (_Float16)(acc[i][j][r] + bv);
      *reinterpret_cast<half4*>(&Vt[(size_t)hh * Dh * Sq + (size_t)d * Sq + pos]) = hv;
    }
  }
}

// ---- Output GEMM: 64x128 tiles (grid 64x8 = 512 blocks = 2/CU) ----
// C^T accumulation, coalesced float4 stores to fp32 [s][1024].
__global__ __launch_bounds__(256) void k_gemmO(
    const unsigned short* __restrict__ A, const unsigned short* __restrict__ Wt,
    const float* __restrict__ bias, float* __restrict__ out) {
  __shared__ __align__(16) unsigned short Al[64 * 64];
  __shared__ __align__(16) unsigned short Bl[128 * 64];
  int t = threadIdx.x;
  int w = t >> 6, L = t & 63, quad = L >> 4, c = L & 15;
  int m0 = blockIdx.x * 64, n0 = blockIdx.y * 128;
  int wm = w & 1, wn = w >> 1;  // wave -> 32-row x 64-col subtile

  f32x4 zero = {0.f, 0.f, 0.f, 0.f};
  f32x4 acc[4][2];
#pragma unroll
  for (int j = 0; j < 4; j++)
#pragma unroll
    for (int i = 0; i < 2; i++) acc[j][i] = zero;

  for (int k0 = 0; k0 < 1024; k0 += 64) {
    __syncthreads();
#pragma unroll
    for (int i = 0; i < 2; i++) {  // A tile 64x64: 512 chunks
      int ch = i * 256 + t;
      int row = ch >> 3, kg = (ch & 7) ^ (row & 7);
      gload16(A + (size_t)(m0 + row) * 1024 + k0 + kg * 8, &Al[ch * 8]);
    }
#pragma unroll
    for (int i = 0; i < 4; i++) {  // B tile 128x64: 1024 chunks
      int ch = i * 256 + t;
      int row = ch >> 3, kg = (ch & 7) ^ (row & 7);
      gload16(Wt + (size_t)(n0 + row) * 1024 + k0 + kg * 8, &Bl[ch * 8]);
    }
    __syncthreads();
#pragma unroll
    for (int ks = 0; ks < 2; ks++) {
      half8 af[2], bfr[4];
#pragma unroll
      for (int i = 0; i < 2; i++) {
        int row = wm * 32 + i * 16 + c;
        int kg = (quad + 4 * ks) ^ (row & 7);
        af[i] = *reinterpret_cast<const half8*>(&Al[row * 64 + kg * 8]);
      }
#pragma unroll
      for (int j = 0; j < 4; j++) {
        int row = wn * 64 + j * 16 + c;
        int kg = (quad + 4 * ks) ^ (row & 7);
        bfr[j] = *reinterpret_cast<const half8*>(&Bl[row * 64 + kg * 8]);
      }
#pragma unroll
      for (int j = 0; j < 4; j++)
#pragma unroll
        for (int i = 0; i < 2; i++)
          acc[j][i] = __builtin_amdgcn_mfma_f32_16x16x32_f16(bfr[j], af[i], acc[j][i], 0, 0, 0);
    }
  }

#pragma unroll
  for (int j = 0; j < 4; j++) {
    int nb4 = n0 + wn * 64 + j * 16 + quad * 4;
    f32x4 b4 = *reinterpret_cast<const f32x4*>(bias + nb4);
#pragma unroll
    for (int i = 0; i < 2; i++) {
      int s = m0 + wm * 32 + i * 16 + c;
      f32x4 v = acc[j][i] + b4;
      *reinterpret_cast<f32x4*>(out + (size_t)s * 1024 + nb4) = v;
    }
  }
}

// ---- flash attention, S^T/O^T form, all-K=32 MFMA, key-parity waves ----
// Q,K [h][s][64] f16 (Q pre-scaled), Vt [h][64][perm(s)] f16 -> O [s][1024] f16
// 512 threads = 8 waves; wave w: parity par=w>>2 (even/odd key tiles),
// wl=w&3 owns 32 q-rows. LDS: [buf][Kev,Kod,Vev,Vod][8KB] = 64KB.
__global__ __launch_bounds__(512, 4) void k_attn(
    const unsigned short* __restrict__ Q, const unsigned short* __restrict__ K,
    const unsigned short* __restrict__ Vt, unsigned short* __restrict__ O) {
  __shared__ __align__(16) unsigned short SM[32768];  // 64 KB
  int t = threadIdx.x;
  int w = t >> 6, L = t & 63, quad = L >> 4, c = L & 15;
  int wl = w & 3, par = w >> 2;
  int h = blockIdx.y, qb = blockIdx.x;
  const unsigned short* Qh = Q + (size_t)h * Sq * Dh;
  const unsigned short* Kh = K + (size_t)h * Sq * Dh;
  const unsigned short* Vth = Vt + (size_t)h * Dh * Sq;

  half8 qf[2][2];
#pragma unroll
  for (int qg = 0; qg < 2; qg++) {
    int qrow = qb * 128 + wl * 32 + qg * 16 + c;
#pragma unroll
    for (int ks = 0; ks < 2; ks++)
      qf[qg][ks] = *reinterpret_cast<const half8*>(Qh + (size_t)qrow * Dh + ks * 32 + quad * 8);
  }

  f32x4 zero = {0.f, 0.f, 0.f, 0.f};
  f32x4 o0[4], o1[4];
#pragma unroll
  for (int i = 0; i < 4; i++) { o0[i] = zero; o1[i] = zero; }
  f32x4 l0 = zero, l1 = zero;
  half8 ones8;
#pragma unroll
  for (int j = 0; j < 8; j++) ones8[j] = (_Float16)1.0f;

  int koff[2][4], voff[4][2];
#pragma unroll
  for (int ks = 0; ks < 2; ks++)
#pragma unroll
    for (int nt = 0; nt < 4; nt++) {
      int row = nt * 16 + c;
      koff[ks][nt] = par * 4096 + row * 64 + (((ks * 4 + quad) ^ (row & 7)) * 8);
    }
#pragma unroll
  for (int dt = 0; dt < 4; dt++)
#pragma unroll
    for (int n2 = 0; n2 < 2; n2++) {
      int row = dt * 16 + c;
      voff[dt][n2] = (2 + par) * 4096 + row * 64 + (((n2 * 4 + quad) ^ (row & 7)) * 8);
    }

  int srow = t >> 3, skg = (t & 7) ^ (srow & 7);
  const unsigned short* Kg = Kh + srow * Dh + skg * 8;          // + tb*4096
  const unsigned short* Vg = Vth + (size_t)srow * Sq + skg * 8; // + tb*64

#pragma unroll
  for (int p2 = 0; p2 < 2; p2++) {
    gload16(Kg + p2 * 4096, &SM[p2 * 4096 + t * 8]);
    gload16(Vg + p2 * 64, &SM[(2 + p2) * 4096 + t * 8]);
  }

  auto body = [&](int BUFOFF) {
    f32x4 st0[4], st1[4];
#pragma unroll
    for (int nt = 0; nt < 4; nt++) { st0[nt] = zero; st1[nt] = zero; }
#pragma unroll
    for (int ks = 0; ks < 2; ks++)
#pragma unroll
      for (int nt = 0; nt < 4; nt++) {
        half8 kfv = *reinterpret_cast<const half8*>(&SM[koff[ks][nt] + BUFOFF]);
        st0[nt] = __builtin_amdgcn_mfma_f32_16x16x32_f16(kfv, qf[0][ks], st0[nt], 0, 0, 0);
        st1[nt] = __builtin_amdgcn_mfma_f32_16x16x32_f16(kfv, qf[1][ks], st1[nt], 0, 0, 0);
      }
    half8 pB0[2], pB1[2];
#pragma unroll
    for (int n2 = 0; n2 < 2; n2++) {
      U8 u;
      u.h2[0] = pk(__builtin_amdgcn_exp2f(st0[2 * n2][0]), __builtin_amdgcn_exp2f(st0[2 * n2][1]));
      u.h2[1] = pk(__builtin_amdgcn_exp2f(st0[2 * n2][2]), __builtin_amdgcn_exp2f(st0[2 * n2][3]));
      u.h2[2] = pk(__builtin_amdgcn_exp2f(st0[2 * n2 + 1][0]), __builtin_amdgcn_exp2f(st0[2 * n2 + 1][1]));
      u.h2[3] = pk(__builtin_amdgcn_exp2f(st0[2 * n2 + 1][2]), __builtin_amdgcn_exp2f(st0[2 * n2 + 1][3]));
      pB0[n2] = u.v8;
      U8 v;
      v.h2[0] = pk(__builtin_amdgcn_exp2f(st1[2 * n2][0]), __builtin_amdgcn_exp2f(st1[2 * n2][1]));
      v.h2[1] = pk(__builtin_amdgcn_exp2f(st1[2 * n2][2]), __builtin_amdgcn_exp2f(st1[2 * n2][3]));
      v.h2[2] = pk(__builtin_amdgcn_exp2f(st1[2 * n2 + 1][0]), __builtin_amdgcn_exp2f(st1[2 * n2 + 1][1]));
      v.h2[3] = pk(__builtin_amdgcn_exp2f(st1[2 * n2 + 1][2]), __builtin_amdgcn_exp2f(st1[2 * n2 + 1][3]));
      pB1[n2] = v.v8;
      l0 = __builtin_amdgcn_mfma_f32_16x16x32_f16(ones8, pB0[n2], l0, 0, 0, 0);
      l1 = __builtin_amdgcn_mfma_f32_16x16x32_f16(ones8, pB1[n2], l1, 0, 0, 0);
    }
#pragma unroll
    for (int dt = 0; dt < 4; dt++)
#pragma unroll
      for (int n2 = 0; n2 < 2; n2++) {
        half8 vv = *reinterpret_cast<const half8*>(&SM[voff[dt][n2] + BUFOFF]);
        o0[dt] = __builtin_amdgcn_mfma_f32_16x16x32_f16(vv, pB0[n2], o0[dt], 0, 0, 0);
        o1[dt] = __builtin_amdgcn_mfma_f32_16x16x32_f16(vv, pB1[n2], o1[dt], 0, 0, 0);
      }
  };

  for (int ob2 = 0; ob2 < 16; ob2++) {
    __syncthreads();
    {
      int tb = 4 * ob2 + 2;
#pragma unroll
      for (int p2 = 0; p2 < 2; p2++) {
        gload16(Kg + (size_t)(tb + p2) * 4096, &SM[16384 + p2 * 4096 + t * 8]);
        gload16(Vg + (tb + p2) * 64, &SM[16384 + (2 + p2) * 4096 + t * 8]);
      }
    }
    body(0);
    __syncthreads();
    if (ob2 < 15) {
      int tb = 4 * ob2 + 4;
#pragma unroll
      for (int p2 = 0; p2 < 2; p2++) {
        gload16(Kg + (size_t)(tb + p2) * 4096, &SM[p2 * 4096 + t * 8]);
        gload16(Vg + (tb + p2) * 64, &SM[(2 + p2) * 4096 + t * 8]);
      }
    }
    body(16384);
  }

  // combine even/odd partials: plain sums -> exact addition.
  __syncthreads();
  float* cb = (float*)SM;  // [wl][vec 0..8][lane] of f32x4 = 36 KB
  if (par == 1) {
#pragma unroll
    for (int v = 0; v < 4; v++) {
      *reinterpret_cast<f32x4*>(cb + ((wl * 9 + v) * 64 + L) * 4) = o0[v];
      *reinterpret_cast<f32x4*>(cb + ((wl * 9 + 4 + v) * 64 + L) * 4) = o1[v];
    }
    f32x4 lv = {l0[0], l1[0], 0.f, 0.f};
    *reinterpret_cast<f32x4*>(cb + ((wl * 9 + 8) * 64 + L) * 4) = lv;
  }
  __syncthreads();
  if (par == 0) {
#pragma unroll
    for (int v = 0; v < 4; v++) {
      o0[v] += *reinterpret_cast<const f32x4*>(cb + ((wl * 9 + v) * 64 + L) * 4);
      o1[v] += *reinterpret_cast<const f32x4*>(cb + ((wl * 9 + 4 + v) * 64 + L) * 4);
    }
    f32x4 lv = *reinterpret_cast<const f32x4*>(cb + ((wl * 9 + 8) * 64 + L) * 4);
    float lt0 = l0[0] + lv[0], lt1 = l1[0] + lv[1];

#pragma unroll
    for (int qg = 0; qg < 2; qg++) {
      float inv = 1.f / (qg ? lt1 : lt0);
      f32x4* oo = qg ? o1 : o0;
      int q = qb * 128 + wl * 32 + qg * 16 + c;
#pragma unroll
      for (int dt = 0; dt < 4; dt++) {
        half4 hv;
#pragma unroll
        for (int r = 0; r < 4; r++) hv[r] = (_Float16)(oo[dt][r] * inv);
        *reinterpret_cast<half4*>(&O[(size_t)q * 1024 + h * 64 + dt * 16 + quad * 4]) = hv;
      }
    }
  }
}

extern "C" void kernel_launch(void* const* d_in, const int* in_sizes, int n_in,
                              void* d_out, int out_size, void* d_ws, size_t ws_size,
                              hipStream_t stream) {
  const float* x  = (const float*)d_in[0];
  const float* Wq = (const float*)d_in[1];
  const float* bq = (const float*)d_in[2];
  const float* Wk = (const float*)d_in[3];
  const float* bk = (const float*)d_in[4];
  const float* Wv = (const float*)d_in[5];
  const float* bv = (const float*)d_in[6];
  const float* Wo = (const float*)d_in[7];
  const float* bo = (const float*)d_in[8];

  char* ws = (char*)d_ws;
  const size_t MB = 1u << 20;
  unsigned short* xb  = (unsigned short*)(ws);            // 8 MB  x as f16
  unsigned short* Wqt = (unsigned short*)(ws + 8 * MB);   // 2 MB each, transposed f16
  unsigned short* Wkt = (unsigned short*)(ws + 10 * MB);
  unsigned short* Wvt = (unsigned short*)(ws + 12 * MB);
  unsigned short* Wot = (unsigned short*)(ws + 14 * MB);
  unsigned short* Qb  = (unsigned short*)(ws + 16 * MB);  // 8 MB [h][s][d]
  unsigned short* Kb  = (unsigned short*)(ws + 24 * MB);  // 8 MB [h][s][d]
  unsigned short* Vtg = (unsigned short*)(ws + 32 * MB);  // 8 MB [h][d][perm(s)]
  unsigned short* Ob  = (unsigned short*)(ws + 40 * MB);  // 8 MB [s][e]  (total 48 MB)

  k_prep<<<5120, 256, 0, stream>>>(x, Wq, Wk, Wv, Wo, xb, Wqt, Wkt, Wvt, Wot);
  k_gemm<<<dim3(32, 8, 3), 256, 0, stream>>>(xb, Wqt, Wkt, Wvt, bq, bk, bv,
                                             (void*)Qb, (void*)Kb, (void*)Vtg);
  k_attn<<<dim3(32, 16), 512, 0, stream>>>(Qb, Kb, Vtg, Ob);
  k_gemmO<<<dim3(64, 8), 256, 0, stream>>>(Ob, Wot, bo, (float*)d_out);
}